// Round 10
// baseline (922.462 us; speedup 1.0000x reference)
//
#include <hip/hip_runtime.h>
#include <math.h>

#define NN 50000
#define NE 800000

#define LRELU(v) ((v) > 0.f ? (v) : 0.2f * (v))

typedef __attribute__((ext_vector_type(4))) float f32x4;
typedef __attribute__((ext_vector_type(8))) short bf16x8;

static __device__ __forceinline__ unsigned short f2bf(float f) {
  union { float f; unsigned int i; } c; c.f = f;
  unsigned int r = c.i + 0x7fff + ((c.i >> 16) & 1);   // RNE
  return (unsigned short)(r >> 16);
}
static __device__ __forceinline__ float bflo(unsigned int u) {
  union { unsigned int i; float f; } c; c.i = u << 16; return c.f;
}
static __device__ __forceinline__ float bfhi(unsigned int u) {
  union { unsigned int i; float f; } c; c.i = u & 0xffff0000u; return c.f;
}

// ---------------------------------------------------------------------------
// conv_wf: W [K][256] fp32 -> fragment-ordered bf16 table
//   wf[((ks*16+n)*64 + l)*8 + j] = bf16(W[ks*32 + (l>>4)*8 + j][n*16 + (l&15)])
// ---------------------------------------------------------------------------
__global__ __launch_bounds__(256)
void conv_wf(const float* __restrict__ W, unsigned short* __restrict__ wf,
             int K) {
  const int g = blockIdx.x * 256 + threadIdx.x;   // K*256 total
  if (g >= K * 256) return;
  const int j = g & 7;
  const int l = (g >> 3) & 63;
  const int fn = g >> 9;
  const int n = fn & 15, ks = fn >> 4;
  const int k = ks * 32 + (l >> 4) * 8 + j;
  const int c = n * 16 + (l & 15);
  wf[g] = f2bf(W[(size_t)k * 256 + c]);
}

// ---------------------------------------------------------------------------
// MFMA node GEMM: outb = bf16(A @ W + b). No LDS; wf streamed from L2.
// ---------------------------------------------------------------------------
template <int KS>   // KS = K/32
__global__ __launch_bounds__(256)
void gemm_mfma(const float* __restrict__ A,
               const unsigned short* __restrict__ wf0,
               const float* __restrict__ b0, unsigned short* __restrict__ outb0,
               const unsigned short* __restrict__ wf1,
               const float* __restrict__ b1, unsigned short* __restrict__ outb1) {
  const unsigned short* wf = blockIdx.y ? wf1 : wf0;
  const float* bias        = blockIdx.y ? b1 : b0;
  unsigned short* outb     = blockIdx.y ? outb1 : outb0;

  const int tid = threadIdx.x;
  const int w = tid >> 6, l = tid & 63;
  const int lid = l & 15, lg = l >> 4;
  const int row  = blockIdx.x * 64 + w * 16 + lid;
  const bool rowok = row < NN;
  const int rowv = rowok ? row : NN - 1;
  const int K = KS * 32;

  bf16x8 bfr[KS];
  const float* ap = A + (size_t)rowv * K + lg * 8;
#pragma unroll
  for (int ks = 0; ks < KS; ++ks) {
    const float4 v0 = *(const float4*)(ap + ks * 32);
    const float4 v1 = *(const float4*)(ap + ks * 32 + 4);
    bf16x8 b;
    b[0]=f2bf(v0.x); b[1]=f2bf(v0.y); b[2]=f2bf(v0.z); b[3]=f2bf(v0.w);
    b[4]=f2bf(v1.x); b[5]=f2bf(v1.y); b[6]=f2bf(v1.z); b[7]=f2bf(v1.w);
    bfr[ks] = b;
  }

  f32x4 acc[16];
#pragma unroll
  for (int n = 0; n < 16; ++n) acc[n] = (f32x4){0.f, 0.f, 0.f, 0.f};

#pragma unroll
  for (int ks = 0; ks < KS; ++ks) {
#pragma unroll
    for (int n = 0; n < 16; ++n) {
      const bf16x8 a = *(const bf16x8*)(wf + ((size_t)(ks * 16 + n) * 64 + l) * 8);
      acc[n] = __builtin_amdgcn_mfma_f32_16x16x32_bf16(a, bfr[ks], acc[n], 0, 0, 0);
    }
  }

  if (rowok) {
#pragma unroll
    for (int n = 0; n < 16; ++n) {
      const int c0 = n * 16 + lg * 4;
      const float4 bv = *(const float4*)(bias + c0);
      ushort4 o;
      o.x = f2bf(acc[n][0] + bv.x); o.y = f2bf(acc[n][1] + bv.y);
      o.z = f2bf(acc[n][2] + bv.z); o.w = f2bf(acc[n][3] + bv.w);
      *(ushort4*)(outb + (size_t)row * 256 + c0) = o;
    }
  }
}

// ---------------------------------------------------------------------------
// WeT prep: wet[c*64+k] = bf16(We[k*256+c]).
// ---------------------------------------------------------------------------
__global__ __launch_bounds__(256)
void conv_wet(const float* __restrict__ We1, unsigned short* __restrict__ wet1,
              const float* __restrict__ We2, unsigned short* __restrict__ wet2) {
  const float* We = blockIdx.y ? We2 : We1;
  unsigned short* wet = blockIdx.y ? wet2 : wet1;
  const int idx = blockIdx.x * 256 + threadIdx.x;
  const int k = idx >> 8, c = idx & 255;
  wet[c * 64 + k] = f2bf(We[(size_t)k * 256 + c]);
}

// ---------------------------------------------------------------------------
// CSR build
// ---------------------------------------------------------------------------
__global__ __launch_bounds__(256)
void dst_hist(const int* __restrict__ dst, int* __restrict__ cnt) {
  const int e = blockIdx.x * 256 + threadIdx.x;
  if (e < NE) atomicAdd(&cnt[dst[e]], 1);
}

__global__ __launch_bounds__(1024)
void exscan(int* __restrict__ cnt, int* __restrict__ row_start,
            int* __restrict__ cur, int n) {
  __shared__ int buf[1024];
  __shared__ int carry;
  if (threadIdx.x == 0) carry = 0;
  __syncthreads();
  for (int base = 0; base < n; base += 1024) {
    const int i = base + threadIdx.x;
    const int v = (i < n) ? cnt[i] : 0;
    buf[threadIdx.x] = v;
    __syncthreads();
    for (int off = 1; off < 1024; off <<= 1) {
      const int t = (threadIdx.x >= off) ? buf[threadIdx.x - off] : 0;
      __syncthreads();
      buf[threadIdx.x] += t;
      __syncthreads();
    }
    const int excl = buf[threadIdx.x] - v + carry;
    if (i < n) { row_start[i] = excl; cur[i] = excl; }
    __syncthreads();
    if (threadIdx.x == 1023) carry += buf[1023];
    __syncthreads();
  }
  if (threadIdx.x == 0) row_start[n] = carry;
}

__global__ __launch_bounds__(256)
void bucket_fill(const int* __restrict__ src, const int* __restrict__ dst,
                 int* __restrict__ cur, int* __restrict__ eid,
                 int* __restrict__ ssrc, int* __restrict__ sdst) {
  const int e = blockIdx.x * 256 + threadIdx.x;
  if (e < NE) {
    const int d = dst[e];
    const int p = atomicAdd(&cur[d], 1);
    eid[p] = e;
    ssrc[p] = src[e];
    sdst[p] = d;
  }
}

// ---------------------------------------------------------------------------
// eab prep: eab[p][c] = bf16(ea[eid[p]][c]).
// ---------------------------------------------------------------------------
__global__ __launch_bounds__(256)
void conv_eab(const float* __restrict__ ea, const int* __restrict__ eid,
              unsigned short* __restrict__ eab) {
  const int g = blockIdx.x * 256 + threadIdx.x;
  const int p = g >> 4, c4 = (g & 15) * 4;
  const int e = eid[p];
  const float4 v = *(const float4*)(ea + (size_t)e * 64 + c4);
  ushort4 o;
  o.x = f2bf(v.x); o.y = f2bf(v.y); o.z = f2bf(v.z); o.w = f2bf(v.w);
  *(ushort4*)(eab + (size_t)p * 64 + c4) = o;
}

// ---------------------------------------------------------------------------
// Edge kernel: swapped-operand MFMA, wet in LDS (fragment order, conflict-free
// staging: dest 16B-unit linear in tid), 32 edges/wave (2 groups share the
// smw reads). Block = 128 CSR positions, 4 waves.
// ---------------------------------------------------------------------------
template <int EAB>
__global__ __launch_bounds__(256)
void edge_logits_swap(const float* __restrict__ ea,
                      const unsigned short* __restrict__ eab,
                      const unsigned short* __restrict__ wet,  // [256][64]
                      const unsigned short* __restrict__ xlb,
                      const unsigned short* __restrict__ xrb,
                      const float* __restrict__ att,
                      const int* __restrict__ eid,
                      const int* __restrict__ ssrc, const int* __restrict__ sdst,
                      float* __restrict__ elog) {
  __shared__ unsigned short smw[2][16][64][8];   // 32 KB

  const int tid = threadIdx.x;
  // stage: dest unit = i*256+tid (linear -> conflict-free ds_write_b128)
#pragma unroll
  for (int i = 0; i < 8; ++i) {
    const int unit = i * 256 + tid;
    const int lane = unit & 63;
    const int n    = (unit >> 6) & 15;
    const int half = unit >> 10;
    const int lid_ = lane & 15, lg_ = lane >> 4;
    const uint4 v = *(const uint4*)(wet + (size_t)(n * 16 + lid_) * 64 +
                                    (half * 4 + lg_) * 8);
    *(uint4*)&smw[half][n][lane][0] = v;
  }
  __syncthreads();

  const int w = tid >> 6, l = tid & 63;
  const int lid = l & 15, lg = l >> 4;
  const int base = blockIdx.x * 128 + w * 32;
  const int pA = base + lid;
  const int pB = base + 16 + lid;
  const int sA = ssrc[pA], dA = sdst[pA];
  const int sB = ssrc[pB], dB = sdst[pB];

  bf16x8 fA0, fA1, fB0, fB1;
  if (EAB) {
    fA0 = *(const bf16x8*)(eab + (size_t)pA * 64 + lg * 8);
    fA1 = *(const bf16x8*)(eab + (size_t)pA * 64 + 32 + lg * 8);
    fB0 = *(const bf16x8*)(eab + (size_t)pB * 64 + lg * 8);
    fB1 = *(const bf16x8*)(eab + (size_t)pB * 64 + 32 + lg * 8);
  } else {
    const int eA = eid[pA], eB = eid[pB];
    const float* apA = ea + (size_t)eA * 64 + lg * 8;
    const float* apB = ea + (size_t)eB * 64 + lg * 8;
#pragma unroll
    for (int g2 = 0; g2 < 2; ++g2) {
      const float* ap = g2 ? apB : apA;
      const float4 v00 = *(const float4*)(ap);
      const float4 v01 = *(const float4*)(ap + 4);
      const float4 v10 = *(const float4*)(ap + 32);
      const float4 v11 = *(const float4*)(ap + 36);
      bf16x8 t0, t1;
      t0[0]=f2bf(v00.x); t0[1]=f2bf(v00.y); t0[2]=f2bf(v00.z); t0[3]=f2bf(v00.w);
      t0[4]=f2bf(v01.x); t0[5]=f2bf(v01.y); t0[6]=f2bf(v01.z); t0[7]=f2bf(v01.w);
      t1[0]=f2bf(v10.x); t1[1]=f2bf(v10.y); t1[2]=f2bf(v10.z); t1[3]=f2bf(v10.w);
      t1[4]=f2bf(v11.x); t1[5]=f2bf(v11.y); t1[6]=f2bf(v11.z); t1[7]=f2bf(v11.w);
      if (g2) { fB0 = t0; fB1 = t1; } else { fA0 = t0; fA1 = t1; }
    }
  }

  const unsigned short* xlpA = xlb + (size_t)sA * 256;
  const unsigned short* xrpA = xrb + (size_t)dA * 256;
  const unsigned short* xlpB = xlb + (size_t)sB * 256;
  const unsigned short* xrpB = xrb + (size_t)dB * 256;

  float phA0=0.f, phA1=0.f, phA2=0.f, phA3=0.f;
  float phB0=0.f, phB1=0.f, phB2=0.f, phB3=0.f;
#pragma unroll
  for (int n = 0; n < 16; ++n) {
    const bf16x8 w0 = *(const bf16x8*)&smw[0][n][l][0];
    const bf16x8 w1 = *(const bf16x8*)&smw[1][n][l][0];
    f32x4 accA = (f32x4){0.f, 0.f, 0.f, 0.f};
    f32x4 accB = (f32x4){0.f, 0.f, 0.f, 0.f};
    accA = __builtin_amdgcn_mfma_f32_16x16x32_bf16(w0, fA0, accA, 0, 0, 0);
    accA = __builtin_amdgcn_mfma_f32_16x16x32_bf16(w1, fA1, accA, 0, 0, 0);
    accB = __builtin_amdgcn_mfma_f32_16x16x32_bf16(w0, fB0, accB, 0, 0, 0);
    accB = __builtin_amdgcn_mfma_f32_16x16x32_bf16(w1, fB1, accB, 0, 0, 0);

    const int c0 = n * 16 + lg * 4;
    const float4 at = *(const float4*)(att + c0);
    float v, pn;
    {
      const uint2 xu = *(const uint2*)(xlpA + c0);
      const uint2 ru = *(const uint2*)(xrpA + c0);
      pn = 0.f;
      v = accA[0] + bflo(xu.x) + bflo(ru.x); v = LRELU(v); pn += v * at.x;
      v = accA[1] + bfhi(xu.x) + bfhi(ru.x); v = LRELU(v); pn += v * at.y;
      v = accA[2] + bflo(xu.y) + bflo(ru.y); v = LRELU(v); pn += v * at.z;
      v = accA[3] + bfhi(xu.y) + bfhi(ru.y); v = LRELU(v); pn += v * at.w;
      if ((n >> 2) == 0) phA0 += pn;
      else if ((n >> 2) == 1) phA1 += pn;
      else if ((n >> 2) == 2) phA2 += pn;
      else phA3 += pn;
    }
    {
      const uint2 xu = *(const uint2*)(xlpB + c0);
      const uint2 ru = *(const uint2*)(xrpB + c0);
      pn = 0.f;
      v = accB[0] + bflo(xu.x) + bflo(ru.x); v = LRELU(v); pn += v * at.x;
      v = accB[1] + bfhi(xu.x) + bfhi(ru.x); v = LRELU(v); pn += v * at.y;
      v = accB[2] + bflo(xu.y) + bflo(ru.y); v = LRELU(v); pn += v * at.z;
      v = accB[3] + bfhi(xu.y) + bfhi(ru.y); v = LRELU(v); pn += v * at.w;
      if ((n >> 2) == 0) phB0 += pn;
      else if ((n >> 2) == 1) phB1 += pn;
      else if ((n >> 2) == 2) phB2 += pn;
      else phB3 += pn;
    }
  }

  phA0 += __shfl_xor(phA0, 16); phA0 += __shfl_xor(phA0, 32);
  phA1 += __shfl_xor(phA1, 16); phA1 += __shfl_xor(phA1, 32);
  phA2 += __shfl_xor(phA2, 16); phA2 += __shfl_xor(phA2, 32);
  phA3 += __shfl_xor(phA3, 16); phA3 += __shfl_xor(phA3, 32);
  phB0 += __shfl_xor(phB0, 16); phB0 += __shfl_xor(phB0, 32);
  phB1 += __shfl_xor(phB1, 16); phB1 += __shfl_xor(phB1, 32);
  phB2 += __shfl_xor(phB2, 16); phB2 += __shfl_xor(phB2, 32);
  phB3 += __shfl_xor(phB3, 16); phB3 += __shfl_xor(phB3, 32);

  const float logitA = (lg == 0) ? phA0 : (lg == 1) ? phA1
                     : (lg == 2) ? phA2 : phA3;
  const float logitB = (lg == 0) ? phB0 : (lg == 1) ? phB1
                     : (lg == 2) ? phB2 : phB3;
  elog[(size_t)pA * 4 + lg] = expf(logitA);
  elog[(size_t)pB * 4 + lg] = expf(logitB);
}

// ---------------------------------------------------------------------------
// Aggregation: one wave per dst node, 4 nodes/block; streams CSR bucket.
// ---------------------------------------------------------------------------
__global__ __launch_bounds__(256)
void aggregate(const unsigned short* __restrict__ xlb,
               const float* __restrict__ elog,
               const int* __restrict__ ssrc, const int* __restrict__ row_start,
               const float* __restrict__ bias, float* __restrict__ out) {
  const int wid  = threadIdx.x >> 6;
  const int lane = threadIdx.x & 63;
  const int d    = blockIdx.x * 4 + wid;
  const int h = lane >> 4;
  const int c = lane * 4;
  float ax = 0.f, ay = 0.f, az = 0.f, aw = 0.f;
  float dtot = 0.f;
  const int beg = row_start[d], end = row_start[d + 1];
  for (int p = beg; p < end; ++p) {
    const float ev = elog[(size_t)p * 4 + h];
    const int s = ssrc[p];
    const uint2 xv = *(const uint2*)(xlb + (size_t)s * 256 + c);
    ax += ev * bflo(xv.x); ay += ev * bfhi(xv.x);
    az += ev * bflo(xv.y); aw += ev * bfhi(xv.y);
    dtot += ev;
  }
  const float inv = 1.f / (dtot + 1e-16f);
  const float4 bv = *(const float4*)(bias + c);
  float4 o;
  o.x = bv.x + ax * inv; o.y = bv.y + ay * inv;
  o.z = bv.z + az * inv; o.w = bv.w + aw * inv;
  *(float4*)(out + (size_t)d * 256 + c) = o;
}

extern "C" void kernel_launch(void* const* d_in, const int* in_sizes, int n_in,
                              void* d_out, int out_size, void* d_ws, size_t ws_size,
                              hipStream_t stream) {
  const float* x    = (const float*)d_in[0];
  const int*   ei   = (const int*)d_in[1];
  const float* ea   = (const float*)d_in[2];
  const float* Wl1  = (const float*)d_in[3];
  const float* bl1  = (const float*)d_in[4];
  const float* Wr1  = (const float*)d_in[5];
  const float* br1  = (const float*)d_in[6];
  const float* We1  = (const float*)d_in[7];
  const float* att1 = (const float*)d_in[8];
  const float* bias1= (const float*)d_in[9];
  const float* Wl2  = (const float*)d_in[10];
  const float* bl2  = (const float*)d_in[11];
  const float* Wr2  = (const float*)d_in[12];
  const float* br2  = (const float*)d_in[13];
  const float* We2  = (const float*)d_in[14];
  const float* att2 = (const float*)d_in[15];
  const float* bias2= (const float*)d_in[16];

  float* out = (float*)d_out;
  float* ws  = (float*)d_ws;

  float* elog = ws;                                    // NE*4 f32
  unsigned short* xlb  = (unsigned short*)(elog + (size_t)NE * 4); // NN*256
  unsigned short* xrb  = xlb + (size_t)NN * 256;       // NN*256
  unsigned short* wet1 = xrb + (size_t)NN * 256;       // 16384
  unsigned short* wet2 = wet1 + 16384;                 // 16384
  unsigned short* wlf1 = wet2 + 16384;                 // 32768
  unsigned short* wrf1 = wlf1 + 32768;                 // 32768
  unsigned short* wlf2 = wrf1 + 32768;                 // 65536
  unsigned short* wrf2 = wlf2 + 65536;                 // 65536
  int* cur       = (int*)(wrf2 + 65536);               // NN
  int* row_start = cur + NN;                           // NN+1
  int* eid       = row_start + NN + 1;                 // NE
  int* ssrc      = eid + NE;                           // NE
  int* sdst      = ssrc + NE;                          // NE
  unsigned short* eab = (unsigned short*)(sdst + NE);  // NE*64 bf16 (optional)
  const size_t need_eab =
      ((char*)(eab + (size_t)NE * 64)) - (char*)d_ws;
  const bool use_eab = ws_size >= need_eab;
  float* h1 = out;  // d_out doubles as h1

  const int* src = ei;
  const int* dst = ei + NE;

  const dim3 ggrid((NN + 63) / 64, 2);   // 782 x 2
  const int  egrid = NE / 128;           // 6250
  const int  epb   = (NE + 255) / 256;
  const int  agrid = NN / 4;             // 12500

  // ---- prep: CSR + bf16 weight tables (+ eab) ----
  hipMemsetAsync(cur, 0, NN * sizeof(int), stream);
  conv_wet<<<dim3(64, 2), 256, 0, stream>>>(We1, wet1, We2, wet2);
  conv_wf<<<128, 256, 0, stream>>>(Wl1, wlf1, 128);
  conv_wf<<<128, 256, 0, stream>>>(Wr1, wrf1, 128);
  conv_wf<<<256, 256, 0, stream>>>(Wl2, wlf2, 256);
  conv_wf<<<256, 256, 0, stream>>>(Wr2, wrf2, 256);
  dst_hist<<<epb, 256, 0, stream>>>(dst, cur);
  exscan<<<1, 1024, 0, stream>>>(cur, row_start, cur, NN);
  bucket_fill<<<epb, 256, 0, stream>>>(src, dst, cur, eid, ssrc, sdst);
  if (use_eab)
    conv_eab<<<NE * 16 / 256, 256, 0, stream>>>(ea, eid, eab);

  // ---- layer 1 ----
  gemm_mfma<4><<<ggrid, 256, 0, stream>>>(x, wlf1, bl1, xlb, wrf1, br1, xrb);
  if (use_eab)
    edge_logits_swap<1><<<egrid, 256, 0, stream>>>(ea, eab, wet1, xlb, xrb,
                                                   att1, eid, ssrc, sdst, elog);
  else
    edge_logits_swap<0><<<egrid, 256, 0, stream>>>(ea, eab, wet1, xlb, xrb,
                                                   att1, eid, ssrc, sdst, elog);
  aggregate<<<agrid, 256, 0, stream>>>(xlb, elog, ssrc, row_start, bias1, h1);

  // ---- layer 2 ----
  gemm_mfma<8><<<ggrid, 256, 0, stream>>>(h1, wlf2, bl2, xlb, wrf2, br2, xrb);
  if (use_eab)
    edge_logits_swap<1><<<egrid, 256, 0, stream>>>(ea, eab, wet2, xlb, xrb,
                                                   att2, eid, ssrc, sdst, elog);
  else
    edge_logits_swap<0><<<egrid, 256, 0, stream>>>(ea, eab, wet2, xlb, xrb,
                                                   att2, eid, ssrc, sdst, elog);
  aggregate<<<agrid, 256, 0, stream>>>(xlb, elog, ssrc, row_start, bias2, out);
}